// Round 2
// baseline (356.621 us; speedup 1.0000x reference)
//
#include <hip/hip_runtime.h>
#include <cstdint>
#include <cstddef>

#define N_DIM 4096
#define M_DIM 4096
#define D_DIM 4096

typedef unsigned short u16;
typedef u16   u16x4 __attribute__((ext_vector_type(4)));
typedef short s16x8 __attribute__((ext_vector_type(8)));   // 8 bf16 in shorts (4 VGPRs)
typedef float f32x4 __attribute__((ext_vector_type(4)));   // MFMA accumulator

// ---------- fp32 -> bf16 (RTNE) ----------
__device__ __forceinline__ u16 f2bf(float f) {
    union { float f; uint32_t u; } v; v.f = f;
    uint32_t u = v.u;
    uint32_t r = u + 0x7fffu + ((u >> 16) & 1u);
    return (u16)(r >> 16);
}

// One fused cast dispatch: lane-contiguous float4 loads (16 B/lane), u16x4 stores.
__global__ __launch_bounds__(256) void convert_both(
    const float* __restrict__ A, const float* __restrict__ B,
    u16* __restrict__ Oa, u16* __restrict__ Ob) {
    const size_t nvec = (size_t)N_DIM * D_DIM / 4;       // float4 units per array
    size_t gid = (size_t)blockIdx.x * blockDim.x + threadIdx.x;
    size_t stride = (size_t)gridDim.x * blockDim.x;
    for (size_t i = gid; i < nvec; i += stride) {
        float4 v = ((const float4*)A)[i];
        u16x4 o; o[0] = f2bf(v.x); o[1] = f2bf(v.y); o[2] = f2bf(v.z); o[3] = f2bf(v.w);
        ((u16x4*)Oa)[i] = o;
    }
    for (size_t i = gid; i < nvec; i += stride) {
        float4 v = ((const float4*)B)[i];
        u16x4 o; o[0] = f2bf(v.x); o[1] = f2bf(v.y); o[2] = f2bf(v.z); o[3] = f2bf(v.w);
        ((u16x4*)Ob)[i] = o;
    }
}

// ---------- async global->LDS, 16B per lane, wave-uniform LDS base ----------
__device__ __forceinline__ void g2l16(const u16* g, u16* l) {
    __builtin_amdgcn_global_load_lds(
        (const __attribute__((address_space(1))) void*)g,
        (__attribute__((address_space(3))) void*)l,
        16, 0, 0);
}

// ---------- 128x128 tile, BK=32, 16x16x32 bf16 MFMA (m97 structure) ----------
// 1D grid of 1024 blocks with an XCD-compact swizzle: assuming round-robin
// block->XCD dispatch (lin % 8), each XCD owns an 8-row x 16-col rectangle of
// tiles -> per-XCD panel footprint 24 MB (vs 36 MB under default row-major).
__global__ __launch_bounds__(256) void gemm_bt_bf16(
    const u16* __restrict__ A, const u16* __restrict__ B, float* __restrict__ C) {
    __shared__ __align__(16) u16 As[128 * 32];
    __shared__ __align__(16) u16 Bs[128 * 32];

    const int tid   = threadIdx.x;
    const int lane  = tid & 63;
    const int wave  = tid >> 6;       // 0..3
    const int waveM = wave >> 1;      // 0..1 (row half)
    const int waveN = wave & 1;       // 0..1 (col half)

    // ---- XCD-compact tile swizzle ----
    const int lin  = blockIdx.x;      // 0..1023
    const int xcd  = lin & 7;
    const int j    = lin >> 3;        // 0..127 within XCD
    const int tileY = (xcd >> 1) * 8  + (j & 7);   // 4 row-groups of 8
    const int tileX = (xcd & 1) * 16 + (j >> 3);   // 2 col-groups of 16

    const int rowBase = tileY * 128;   // N dim (A rows / C rows)
    const int colBase = tileX * 128;   // M dim (B rows / C cols)

    f32x4 acc[4][4] = {};

    // A/B-operand fragment addressing: elem[m = lane&15][k = (lane>>4)*8 + j]
    const int frag_row = lane & 15;
    const int frag_k   = (lane >> 4) * 8;

    for (int kt = 0; kt < D_DIM; kt += 32) {
        __syncthreads();  // previous iter's ds_reads done before overwrite
        const u16* Ag = A + (size_t)rowBase * D_DIM + kt;
        const u16* Bg = B + (size_t)colBase * D_DIM + kt;
        // tile = 128 rows x 64 B = 512 chunks of 16 B; 8 wave-calls of 64 lanes
        #pragma unroll
        for (int jj = 0; jj < 2; ++jj) {
            int grp = jj * 4 + wave;         // wave-uniform 0..7
            int c   = grp * 64 + lane;       // chunk id 0..511
            int r   = c >> 2;                // tile row
            int cc  = (c & 3) * 8;           // bf16 col offset within row
            g2l16(Ag + (size_t)r * D_DIM + cc, &As[grp * 512]);
            g2l16(Bg + (size_t)r * D_DIM + cc, &Bs[grp * 512]);
        }
        __syncthreads();  // compiler drains vmcnt before s_barrier

        s16x8 af[4], bf[4];
        #pragma unroll
        for (int mt = 0; mt < 4; ++mt) {
            int row = waveM * 64 + mt * 16 + frag_row;
            af[mt] = *(const s16x8*)&As[row * 32 + frag_k];
        }
        #pragma unroll
        for (int nt = 0; nt < 4; ++nt) {
            int row = waveN * 64 + nt * 16 + frag_row;
            bf[nt] = *(const s16x8*)&Bs[row * 32 + frag_k];
        }
        #pragma unroll
        for (int mt = 0; mt < 4; ++mt)
            #pragma unroll
            for (int nt = 0; nt < 4; ++nt)
                acc[mt][nt] = __builtin_amdgcn_mfma_f32_16x16x32_bf16(
                    af[mt], bf[nt], acc[mt][nt], 0, 0, 0);
    }

    // Epilogue. C/D layout (verified m89/m91): col = lane&15, row = (lane>>4)*4 + reg
    #pragma unroll
    for (int mt = 0; mt < 4; ++mt) {
        int gr0 = rowBase + waveM * 64 + mt * 16 + (lane >> 4) * 4;
        #pragma unroll
        for (int nt = 0; nt < 4; ++nt) {
            int gc = colBase + waveN * 64 + nt * 16 + (lane & 15);
            #pragma unroll
            for (int r = 0; r < 4; ++r)
                C[(size_t)(gr0 + r) * M_DIM + gc] = acc[mt][nt][r];
        }
    }
}

extern "C" void kernel_launch(void* const* d_in, const int* in_sizes, int n_in,
                              void* d_out, int out_size, void* d_ws, size_t ws_size,
                              hipStream_t stream) {
    const float* A32 = (const float*)d_in[0];   // [N, D] fp32
    const float* B32 = (const float*)d_in[1];   // [M, D] fp32
    float* C = (float*)d_out;                   // [N, M] fp32

    u16* Abf = (u16*)d_ws;                              // 32 MB
    u16* Bbf = Abf + (size_t)N_DIM * D_DIM;             // 32 MB

    convert_both<<<4096, 256, 0, stream>>>(A32, B32, Abf, Bbf);

    gemm_bt_bf16<<<1024, 256, 0, stream>>>(Abf, Bbf, C);
}

// Round 3
// 332.189 us; speedup vs baseline: 1.0736x; 1.0736x over previous
//
#include <hip/hip_runtime.h>
#include <cstdint>
#include <cstddef>

#define N_DIM 4096
#define M_DIM 4096
#define D_DIM 4096

typedef unsigned short u16;
typedef u16   u16x4 __attribute__((ext_vector_type(4)));
typedef short s16x8 __attribute__((ext_vector_type(8)));   // 8 bf16 (4 VGPRs)
typedef float f32x4 __attribute__((ext_vector_type(4)));   // MFMA accumulator

// ---------- fp32 -> bf16 (RTNE) ----------
__device__ __forceinline__ u16 f2bf(float f) {
    union { float f; uint32_t u; } v; v.f = f;
    uint32_t u = v.u;
    uint32_t r = u + 0x7fffu + ((u >> 16) & 1u);
    return (u16)(r >> 16);
}

__global__ __launch_bounds__(256) void convert_both(
    const float* __restrict__ A, const float* __restrict__ B,
    u16* __restrict__ Oa, u16* __restrict__ Ob) {
    const size_t nvec = (size_t)N_DIM * D_DIM / 4;
    size_t gid = (size_t)blockIdx.x * blockDim.x + threadIdx.x;
    size_t stride = (size_t)gridDim.x * blockDim.x;
    for (size_t i = gid; i < nvec; i += stride) {
        float4 v = ((const float4*)A)[i];
        u16x4 o; o[0] = f2bf(v.x); o[1] = f2bf(v.y); o[2] = f2bf(v.z); o[3] = f2bf(v.w);
        ((u16x4*)Oa)[i] = o;
    }
    for (size_t i = gid; i < nvec; i += stride) {
        float4 v = ((const float4*)B)[i];
        u16x4 o; o[0] = f2bf(v.x); o[1] = f2bf(v.y); o[2] = f2bf(v.z); o[3] = f2bf(v.w);
        ((u16x4*)Ob)[i] = o;
    }
}

// ---------- async global->LDS, 16B/lane, wave-uniform LDS base ----------
__device__ __forceinline__ void g2l16(const u16* g, u16* l) {
    __builtin_amdgcn_global_load_lds(
        (const __attribute__((address_space(1))) void*)g,
        (__attribute__((address_space(3))) void*)l,
        16, 0, 0);
}

// XOR bank swizzle: chunk (row r, col-block cb of 8 bf16) lives at slot
// r*4 + (cb ^ perm4(r)). perm4 spreads r=0..7 across all 8 bank-groups
// -> conflict-free ds_read_b128 phases. Inverse applied at staging time by
// permuting the GLOBAL source address (LDS dest of global_load_lds must stay
// wave-uniform-base + lane*16).
__device__ __forceinline__ int perm4(int r) { return (r + (r >> 2)) & 3; }

// stage one 128x32 bf16 tile (8 KB): 512 chunks of 16 B, 8 wave-calls
__device__ __forceinline__ void stage_tile(const u16* __restrict__ G,
                                           u16* lds, int wave, int lane) {
    #pragma unroll
    for (int jj = 0; jj < 2; ++jj) {
        int grp = jj * 4 + wave;         // wave-uniform 0..7
        int s   = grp * 64 + lane;       // LDS slot this lane fills
        int r   = s >> 2;                // tile row that must land here
        int cb  = (s & 3) ^ perm4(r);    // inverse swizzle -> global chunk
        g2l16(G + (size_t)r * D_DIM + cb * 8, lds + grp * 512);
    }
}

__device__ __forceinline__ void compute_tile(const u16* __restrict__ Ac,
                                             const u16* __restrict__ Bc,
                                             f32x4 (&acc)[4][4],
                                             int waveM, int waveN, int lane) {
    const int fr  = lane & 15;      // frag row: m = lane&15
    const int cbq = lane >> 4;      // frag k-block: k = (lane>>4)*8 + j
    s16x8 af[4], bf[4];
    #pragma unroll
    for (int mt = 0; mt < 4; ++mt) {
        int row = waveM * 64 + mt * 16 + fr;
        af[mt] = *(const s16x8*)&Ac[(row * 4 + (cbq ^ perm4(row))) * 8];
    }
    #pragma unroll
    for (int nt = 0; nt < 4; ++nt) {
        int row = waveN * 64 + nt * 16 + fr;
        bf[nt] = *(const s16x8*)&Bc[(row * 4 + (cbq ^ perm4(row))) * 8];
    }
    #pragma unroll
    for (int mt = 0; mt < 4; ++mt)
        #pragma unroll
        for (int nt = 0; nt < 4; ++nt)
            acc[mt][nt] = __builtin_amdgcn_mfma_f32_16x16x32_bf16(
                af[mt], bf[nt], acc[mt][nt], 0, 0, 0);
}

// 128x128 tile, BK=32, double-buffered LDS, one barrier per K-iter.
__global__ __launch_bounds__(256) void gemm_bt_bf16(
    const u16* __restrict__ A, const u16* __restrict__ B, float* __restrict__ C) {
    __shared__ __align__(16) u16 As0[4096], Bs0[4096];   // 8 KB each
    __shared__ __align__(16) u16 As1[4096], Bs1[4096];   // dbuf: 32 KB total

    const int tid   = threadIdx.x;
    const int lane  = tid & 63;
    const int wave  = tid >> 6;
    const int waveM = wave >> 1;
    const int waveN = wave & 1;

    // XCD-compact tile swizzle (round-robin lin%8 -> XCD)
    const int lin  = blockIdx.x;
    const int xcd  = lin & 7;
    const int j    = lin >> 3;
    const int tileY = (xcd >> 1) * 8  + (j & 7);
    const int tileX = (xcd & 1) * 16 + (j >> 3);
    const int rowBase = tileY * 128;
    const int colBase = tileX * 128;

    const u16* Abase = A + (size_t)rowBase * D_DIM;
    const u16* Bbase = B + (size_t)colBase * D_DIM;

    f32x4 acc[4][4] = {};

    // prologue: stage tile 0 into buffer 0
    stage_tile(Abase, As0, wave, lane);
    stage_tile(Bbase, Bs0, wave, lane);

    for (int t = 0; t < 128; t += 2) {
        __syncthreads();   // drains stage(t) (hidden behind prev compute)
        stage_tile(Abase + (t + 1) * 32, As1, wave, lane);   // prefetch t+1
        stage_tile(Bbase + (t + 1) * 32, Bs1, wave, lane);
        compute_tile(As0, Bs0, acc, waveM, waveN, lane);

        __syncthreads();   // drains stage(t+1) (hidden behind compute above)
        if (t + 2 < 128) {
            stage_tile(Abase + (t + 2) * 32, As0, wave, lane); // prefetch t+2
            stage_tile(Bbase + (t + 2) * 32, Bs0, wave, lane);
        }
        compute_tile(As1, Bs1, acc, waveM, waveN, lane);
    }

    // Epilogue. C/D layout (verified m89/m91): col = lane&15, row = (lane>>4)*4 + reg
    #pragma unroll
    for (int mt = 0; mt < 4; ++mt) {
        int gr0 = rowBase + waveM * 64 + mt * 16 + (lane >> 4) * 4;
        #pragma unroll
        for (int nt = 0; nt < 4; ++nt) {
            int gc = colBase + waveN * 64 + nt * 16 + (lane & 15);
            #pragma unroll
            for (int r = 0; r < 4; ++r)
                C[(size_t)(gr0 + r) * M_DIM + gc] = acc[mt][nt][r];
        }
    }
}

extern "C" void kernel_launch(void* const* d_in, const int* in_sizes, int n_in,
                              void* d_out, int out_size, void* d_ws, size_t ws_size,
                              hipStream_t stream) {
    const float* A32 = (const float*)d_in[0];
    const float* B32 = (const float*)d_in[1];
    float* C = (float*)d_out;

    u16* Abf = (u16*)d_ws;
    u16* Bbf = Abf + (size_t)N_DIM * D_DIM;

    convert_both<<<4096, 256, 0, stream>>>(A32, B32, Abf, Bbf);
    gemm_bt_bf16<<<1024, 256, 0, stream>>>(Abf, Bbf, C);
}

// Round 4
// 287.292 us; speedup vs baseline: 1.2413x; 1.1563x over previous
//
#include <hip/hip_runtime.h>
#include <cstdint>
#include <cstddef>

#define N_DIM 4096
#define M_DIM 4096
#define D_DIM 4096

typedef unsigned short u16;
typedef u16   u16x4 __attribute__((ext_vector_type(4)));
typedef short s16x8 __attribute__((ext_vector_type(8)));   // 8 bf16 (4 VGPRs)
typedef float f32x4 __attribute__((ext_vector_type(4)));   // MFMA accumulator

// ---------- fp32 -> bf16 (RTNE) ----------
__device__ __forceinline__ u16 f2bf(float f) {
    union { float f; uint32_t u; } v; v.f = f;
    uint32_t u = v.u;
    uint32_t r = u + 0x7fffu + ((u >> 16) & 1u);
    return (u16)(r >> 16);
}

__global__ __launch_bounds__(256) void convert_both(
    const float* __restrict__ A, const float* __restrict__ B,
    u16* __restrict__ Oa, u16* __restrict__ Ob) {
    const size_t nvec = (size_t)N_DIM * D_DIM / 4;
    size_t gid = (size_t)blockIdx.x * blockDim.x + threadIdx.x;
    size_t stride = (size_t)gridDim.x * blockDim.x;
    for (size_t i = gid; i < nvec; i += stride) {
        float4 v = ((const float4*)A)[i];
        u16x4 o; o[0] = f2bf(v.x); o[1] = f2bf(v.y); o[2] = f2bf(v.z); o[3] = f2bf(v.w);
        ((u16x4*)Oa)[i] = o;
    }
    for (size_t i = gid; i < nvec; i += stride) {
        float4 v = ((const float4*)B)[i];
        u16x4 o; o[0] = f2bf(v.x); o[1] = f2bf(v.y); o[2] = f2bf(v.z); o[3] = f2bf(v.w);
        ((u16x4*)Ob)[i] = o;
    }
}

// ---------- async global->LDS, 16B/lane, wave-uniform LDS base ----------
__device__ __forceinline__ void g2l16(const u16* g, u16* l) {
    __builtin_amdgcn_global_load_lds(
        (const __attribute__((address_space(1))) void*)g,
        (__attribute__((address_space(3))) void*)l,
        16, 0, 0);
}

// XOR bank swizzle: chunk (row r, col-block cb of 8 bf16) lives at slot
// r*4 + (cb ^ perm4(r)); perm4 spreads consecutive rows over all 8 LDS
// bank-groups -> conflict-free ds_read_b128 phases. Inverse applied at
// staging time by permuting the GLOBAL source address (LDS dest of
// global_load_lds must stay wave-uniform-base + lane*16).
__device__ __forceinline__ int perm4(int r) { return (r + (r >> 2)) & 3; }

// stage one 256x32 bf16 tile (16 KB): 1024 chunks of 16 B, 16 wave-calls
// across 8 waves (512-thread block).
__device__ __forceinline__ void stage_tile(const u16* __restrict__ G,
                                           u16* lds, int wave, int lane) {
    #pragma unroll
    for (int jj = 0; jj < 2; ++jj) {
        int grp = jj * 8 + wave;         // wave-uniform 0..15
        int s   = grp * 64 + lane;       // LDS slot this lane fills (0..1023)
        int r   = s >> 2;                // tile row that must land here
        int cb  = (s & 3) ^ perm4(r);    // inverse swizzle -> global chunk
        g2l16(G + (size_t)r * D_DIM + cb * 8, lds + grp * 512);
    }
}

// one wave computes a 128x64 sub-tile: mt 0..7 (M), nt 0..3 (N)
__device__ __forceinline__ void compute_tile(const u16* __restrict__ Ac,
                                             const u16* __restrict__ Bc,
                                             f32x4 (&acc)[8][4],
                                             int waveM, int waveN, int lane) {
    const int fr  = lane & 15;      // frag row: m = lane&15
    const int cbq = lane >> 4;      // frag k-block: k = (lane>>4)*8 + j
    s16x8 af[8], bf[4];
    #pragma unroll
    for (int mt = 0; mt < 8; ++mt) {
        int row = waveM * 128 + mt * 16 + fr;
        af[mt] = *(const s16x8*)&Ac[(row * 4 + (cbq ^ perm4(row))) * 8];
    }
    #pragma unroll
    for (int nt = 0; nt < 4; ++nt) {
        int row = waveN * 64 + nt * 16 + fr;
        bf[nt] = *(const s16x8*)&Bc[(row * 4 + (cbq ^ perm4(row))) * 8];
    }
    #pragma unroll
    for (int mt = 0; mt < 8; ++mt)
        #pragma unroll
        for (int nt = 0; nt < 4; ++nt)
            acc[mt][nt] = __builtin_amdgcn_mfma_f32_16x16x32_bf16(
                af[mt], bf[nt], acc[mt][nt], 0, 0, 0);
}

// 256x256 macro-tile, BK=32, double-buffered LDS (64 KB), 512 threads.
// Staging traffic: 256 blocks x 4 MB = 1.05 GB (half of the 128-tile version)
// -> attacks the observed 11.5 TB/s L2/L3 staging ceiling.
__global__ __launch_bounds__(512) void gemm_bt_bf16(
    const u16* __restrict__ A, const u16* __restrict__ B, float* __restrict__ C) {
    __shared__ __align__(16) u16 As0[8192], Bs0[8192];   // 16 KB each
    __shared__ __align__(16) u16 As1[8192], Bs1[8192];

    const int tid   = threadIdx.x;
    const int lane  = tid & 63;
    const int wave  = tid >> 6;       // 0..7
    const int waveM = wave >> 2;      // 0..1
    const int waveN = wave & 3;       // 0..3

    // XCD-compact swizzle: 256 blocks, 16x16 tile grid; each XCD (lin%8)
    // owns a 4x8 tile rectangle (A 8 MB + B 16 MB panel footprint).
    const int lin  = blockIdx.x;
    const int xcd  = lin & 7;
    const int j    = lin >> 3;                    // 0..31
    const int tileY = (xcd >> 1) * 4 + (j & 3);   // 0..15
    const int tileX = (xcd & 1) * 8 + (j >> 2);   // 0..15
    const int rowBase = tileY * 256;
    const int colBase = tileX * 256;

    const u16* Abase = A + (size_t)rowBase * D_DIM;
    const u16* Bbase = B + (size_t)colBase * D_DIM;

    f32x4 acc[8][4] = {};

    // prologue: stage tile 0 into buffer 0
    stage_tile(Abase, As0, wave, lane);
    stage_tile(Bbase, Bs0, wave, lane);

    for (int t = 0; t < 128; t += 2) {
        __syncthreads();   // drains stage(t) — hidden behind previous compute
        stage_tile(Abase + (t + 1) * 32, As1, wave, lane);   // prefetch t+1
        stage_tile(Bbase + (t + 1) * 32, Bs1, wave, lane);
        compute_tile(As0, Bs0, acc, waveM, waveN, lane);

        __syncthreads();   // drains stage(t+1) — hidden behind compute above
        if (t + 2 < 128) {
            stage_tile(Abase + (t + 2) * 32, As0, wave, lane); // prefetch t+2
            stage_tile(Bbase + (t + 2) * 32, Bs0, wave, lane);
        }
        compute_tile(As1, Bs1, acc, waveM, waveN, lane);
    }

    // Epilogue. C/D layout (verified m89/m91): col = lane&15, row = (lane>>4)*4 + reg
    #pragma unroll
    for (int mt = 0; mt < 8; ++mt) {
        int gr0 = rowBase + waveM * 128 + mt * 16 + (lane >> 4) * 4;
        #pragma unroll
        for (int nt = 0; nt < 4; ++nt) {
            int gc = colBase + waveN * 64 + nt * 16 + (lane & 15);
            #pragma unroll
            for (int r = 0; r < 4; ++r)
                C[(size_t)(gr0 + r) * M_DIM + gc] = acc[mt][nt][r];
        }
    }
}

extern "C" void kernel_launch(void* const* d_in, const int* in_sizes, int n_in,
                              void* d_out, int out_size, void* d_ws, size_t ws_size,
                              hipStream_t stream) {
    const float* A32 = (const float*)d_in[0];
    const float* B32 = (const float*)d_in[1];
    float* C = (float*)d_out;

    u16* Abf = (u16*)d_ws;
    u16* Bbf = Abf + (size_t)N_DIM * D_DIM;

    convert_both<<<4096, 256, 0, stream>>>(A32, B32, Abf, Bbf);
    gemm_bt_bf16<<<256, 512, 0, stream>>>(Abf, Bbf, C);
}

// Round 5
// 274.292 us; speedup vs baseline: 1.3002x; 1.0474x over previous
//
#include <hip/hip_runtime.h>
#include <cstdint>
#include <cstddef>

#define N_DIM 4096
#define M_DIM 4096
#define D_DIM 4096

typedef unsigned short u16;
typedef u16   u16x4 __attribute__((ext_vector_type(4)));
typedef short s16x8 __attribute__((ext_vector_type(8)));   // 8 bf16 (4 VGPRs)
typedef float f32x4 __attribute__((ext_vector_type(4)));   // MFMA accumulator

// ---------- fp32 -> bf16 (RTNE) ----------
__device__ __forceinline__ u16 f2bf(float f) {
    union { float f; uint32_t u; } v; v.f = f;
    uint32_t u = v.u;
    uint32_t r = u + 0x7fffu + ((u >> 16) & 1u);
    return (u16)(r >> 16);
}

__global__ __launch_bounds__(256) void convert_both(
    const float* __restrict__ A, const float* __restrict__ B,
    u16* __restrict__ Oa, u16* __restrict__ Ob) {
    const size_t nvec = (size_t)N_DIM * D_DIM / 4;
    size_t gid = (size_t)blockIdx.x * blockDim.x + threadIdx.x;
    size_t stride = (size_t)gridDim.x * blockDim.x;
    for (size_t i = gid; i < nvec; i += stride) {
        float4 v = ((const float4*)A)[i];
        u16x4 o; o[0] = f2bf(v.x); o[1] = f2bf(v.y); o[2] = f2bf(v.z); o[3] = f2bf(v.w);
        ((u16x4*)Oa)[i] = o;
    }
    for (size_t i = gid; i < nvec; i += stride) {
        float4 v = ((const float4*)B)[i];
        u16x4 o; o[0] = f2bf(v.x); o[1] = f2bf(v.y); o[2] = f2bf(v.z); o[3] = f2bf(v.w);
        ((u16x4*)Ob)[i] = o;
    }
}

// ---------- async global->LDS, 16B/lane, wave-uniform LDS base ----------
__device__ __forceinline__ void g2l16(const u16* g, u16* l) {
    __builtin_amdgcn_global_load_lds(
        (const __attribute__((address_space(1))) void*)g,
        (__attribute__((address_space(3))) void*)l,
        16, 0, 0);
}

// BK=64 tile: each row = 64 bf16 = 128 B = 8 chunks of 16 B (exactly 32 banks).
// XOR swizzle: chunk (row r, logical chunk c) stored at physical chunk
// c ^ (r&7). Fragment reads (16 rows x 1 chunk per quad) then hit all 8
// bank-groups at 2 lanes each -> 2-way access, free (m136). Inverse applied
// at staging by permuting the GLOBAL source chunk (LDS dest of
// global_load_lds must stay wave-uniform-base + lane*16).

// stage one 256x64 bf16 tile (32 KB): 2048 chunks, 4 wave-calls x 8 waves
__device__ __forceinline__ void stage_tile(const u16* __restrict__ G,
                                           u16* lds, int wave, int lane) {
    #pragma unroll
    for (int jj = 0; jj < 4; ++jj) {
        int grp = jj * 8 + wave;         // wave-uniform 0..31
        int s   = grp * 64 + lane;       // LDS slot this lane fills (0..2047)
        int r   = s >> 3;                // tile row that must land here
        int cb  = (s & 7) ^ (r & 7);     // inverse swizzle -> global chunk
        g2l16(G + (size_t)r * D_DIM + cb * 8, lds + grp * 512);
    }
}

// one wave computes a 128x64 sub-tile over BK=64 (two 32-K MFMA slices)
__device__ __forceinline__ void compute_tile(const u16* __restrict__ Ac,
                                             const u16* __restrict__ Bc,
                                             f32x4 (&acc)[8][4],
                                             int waveM, int waveN, int lane) {
    const int fr  = lane & 15;      // frag row: m = lane&15
    const int cbq = lane >> 4;      // frag k-chunk within 32-K slice (0..3)
    #pragma unroll
    for (int ks = 0; ks < 2; ++ks) {
        s16x8 af[8], bf[4];
        #pragma unroll
        for (int mt = 0; mt < 8; ++mt) {
            int row = waveM * 128 + mt * 16 + fr;
            int ph  = (ks * 4 + cbq) ^ (row & 7);
            af[mt] = *(const s16x8*)&Ac[row * 64 + ph * 8];
        }
        #pragma unroll
        for (int nt = 0; nt < 4; ++nt) {
            int row = waveN * 64 + nt * 16 + fr;
            int ph  = (ks * 4 + cbq) ^ (row & 7);
            bf[nt] = *(const s16x8*)&Bc[row * 64 + ph * 8];
        }
        #pragma unroll
        for (int mt = 0; mt < 8; ++mt)
            #pragma unroll
            for (int nt = 0; nt < 4; ++nt)
                acc[mt][nt] = __builtin_amdgcn_mfma_f32_16x16x32_bf16(
                    af[mt], bf[nt], acc[mt][nt], 0, 0, 0);
    }
}

// 256x256 macro-tile, BK=64, double-buffered LDS (128 KB), 512 threads.
// Compute per stage phase (~620 cyc/SIMD) now covers L3 load latency (~600).
__global__ __launch_bounds__(512) void gemm_bt_bf16(
    const u16* __restrict__ A, const u16* __restrict__ B, float* __restrict__ C) {
    __shared__ __align__(16) u16 As0[16384], Bs0[16384];   // 32 KB each
    __shared__ __align__(16) u16 As1[16384], Bs1[16384];   // 128 KB total

    const int tid   = threadIdx.x;
    const int lane  = tid & 63;
    const int wave  = tid >> 6;       // 0..7
    const int waveM = wave >> 2;      // 0..1
    const int waveN = wave & 3;       // 0..3

    // XCD-compact swizzle: 256 blocks, 16x16 tile grid; each XCD (lin%8)
    // owns a 4x8 tile rectangle.
    const int lin  = blockIdx.x;
    const int xcd  = lin & 7;
    const int j    = lin >> 3;                    // 0..31
    const int tileY = (xcd >> 1) * 4 + (j & 3);   // 0..15
    const int tileX = (xcd & 1) * 8 + (j >> 2);   // 0..15
    const int rowBase = tileY * 256;
    const int colBase = tileX * 256;

    const u16* Abase = A + (size_t)rowBase * D_DIM;
    const u16* Bbase = B + (size_t)colBase * D_DIM;

    f32x4 acc[8][4] = {};

    // prologue: stage K-tile 0 into buffer 0
    stage_tile(Abase, As0, wave, lane);
    stage_tile(Bbase, Bs0, wave, lane);

    // 64 K-tiles of depth 64, unrolled x2 over the two buffers
    for (int t = 0; t < 64; t += 2) {
        __syncthreads();   // drains stage(t) — hidden behind previous compute
        stage_tile(Abase + (t + 1) * 64, As1, wave, lane);   // prefetch t+1
        stage_tile(Bbase + (t + 1) * 64, Bs1, wave, lane);
        compute_tile(As0, Bs0, acc, waveM, waveN, lane);

        __syncthreads();   // drains stage(t+1) — hidden behind compute above
        if (t + 2 < 64) {
            stage_tile(Abase + (t + 2) * 64, As0, wave, lane); // prefetch t+2
            stage_tile(Bbase + (t + 2) * 64, Bs0, wave, lane);
        }
        compute_tile(As1, Bs1, acc, waveM, waveN, lane);
    }

    // Epilogue. C/D layout (verified m89/m91): col = lane&15, row = (lane>>4)*4 + reg
    #pragma unroll
    for (int mt = 0; mt < 8; ++mt) {
        int gr0 = rowBase + waveM * 128 + mt * 16 + (lane >> 4) * 4;
        #pragma unroll
        for (int nt = 0; nt < 4; ++nt) {
            int gc = colBase + waveN * 64 + nt * 16 + (lane & 15);
            #pragma unroll
            for (int r = 0; r < 4; ++r)
                C[(size_t)(gr0 + r) * M_DIM + gc] = acc[mt][nt][r];
        }
    }
}

extern "C" void kernel_launch(void* const* d_in, const int* in_sizes, int n_in,
                              void* d_out, int out_size, void* d_ws, size_t ws_size,
                              hipStream_t stream) {
    const float* A32 = (const float*)d_in[0];
    const float* B32 = (const float*)d_in[1];
    float* C = (float*)d_out;

    u16* Abf = (u16*)d_ws;
    u16* Bbf = Abf + (size_t)N_DIM * D_DIM;

    convert_both<<<4096, 256, 0, stream>>>(A32, B32, Abf, Bbf);
    gemm_bt_bf16<<<256, 512, 0, stream>>>(Abf, Bbf, C);
}